// Round 1
// baseline (15513.689 us; speedup 1.0000x reference)
//
#include <hip/hip_runtime.h>
#include <math.h>

// ---------------- common types ----------------
typedef __attribute__((ext_vector_type(8))) short bf16x8;
typedef __attribute__((ext_vector_type(4))) float f32x4;

__device__ __forceinline__ unsigned short f2bf(float x) {
    unsigned u = __float_as_uint(x);
    unsigned r = (u + 0x7FFF + ((u >> 16) & 1)) >> 16;
    return (unsigned short)r;
}
__device__ __forceinline__ float bf_lo(unsigned u) { return __uint_as_float(u << 16); }
__device__ __forceinline__ float bf_hi(unsigned u) { return __uint_as_float(u & 0xffff0000u); }

#define ACT_NONE  0
#define ACT_RELU  1
#define ACT_RELU2 2

// ---------------- MFMA GEMM: C[M,N] = act(A[M,K] @ B[N,K]^T + bias[N]) ----------------
// 64x64 tile, BK=32, 256 threads (4 waves, each 32x32 via 2x2 of 16x16x32 mfma).
// GATHER: A row r comes from A[ids[r]*K] (embedding gather).
// TRANSOUT: write C as kT[b][n][s] with row=(b*1024+s), N<=1024 assumed.
template <int ACT, bool GATHER, bool TRANSOUT>
__global__ __launch_bounds__(256) void gemm_bt(
    const float* __restrict__ A, const float* __restrict__ Bm,
    const float* __restrict__ bias, float* __restrict__ C,
    const int* __restrict__ ids, int M, int N, int K)
{
    __shared__ unsigned short as_[64][40];
    __shared__ unsigned short bs_[64][40];

    const int tid = threadIdx.x;
    const int bm = blockIdx.x, bn = blockIdx.y;
    const int r = tid >> 2, seg = tid & 3;          // staging: row 0..63, k-segment 0..3 (8 floats)

    const int arow = bm * 64 + r;
    const float* aptr = GATHER ? (A + (size_t)ids[arow] * K) : (A + (size_t)arow * K);
    const float* bptr = Bm + (size_t)(bn * 64 + r) * K;

    const int w = tid >> 6, lane = tid & 63;
    const int wr = w >> 1, wc = w & 1;
    const int al = lane & 15, kq = lane >> 4;       // kq in 0..3

    f32x4 acc[2][2];
    for (int mi = 0; mi < 2; ++mi)
        for (int ni = 0; ni < 2; ++ni)
            acc[mi][ni] = (f32x4){0.f, 0.f, 0.f, 0.f};

    for (int k0 = 0; k0 < K; k0 += 32) {
        __syncthreads();
        {
            const float4* ap4 = (const float4*)(aptr + k0 + seg * 8);
            float4 a0 = ap4[0], a1 = ap4[1];
            uint4 pk;
            pk.x = (unsigned)f2bf(a0.x) | ((unsigned)f2bf(a0.y) << 16);
            pk.y = (unsigned)f2bf(a0.z) | ((unsigned)f2bf(a0.w) << 16);
            pk.z = (unsigned)f2bf(a1.x) | ((unsigned)f2bf(a1.y) << 16);
            pk.w = (unsigned)f2bf(a1.z) | ((unsigned)f2bf(a1.w) << 16);
            *(uint4*)&as_[r][seg * 8] = pk;

            const float4* bp4 = (const float4*)(bptr + k0 + seg * 8);
            float4 b0 = bp4[0], b1 = bp4[1];
            pk.x = (unsigned)f2bf(b0.x) | ((unsigned)f2bf(b0.y) << 16);
            pk.y = (unsigned)f2bf(b0.z) | ((unsigned)f2bf(b0.w) << 16);
            pk.z = (unsigned)f2bf(b1.x) | ((unsigned)f2bf(b1.y) << 16);
            pk.w = (unsigned)f2bf(b1.z) | ((unsigned)f2bf(b1.w) << 16);
            *(uint4*)&bs_[r][seg * 8] = pk;
        }
        __syncthreads();

        bf16x8 af[2], bfr[2];
        af[0]  = *(const bf16x8*)&as_[wr * 32 + al][kq * 8];
        af[1]  = *(const bf16x8*)&as_[wr * 32 + 16 + al][kq * 8];
        bfr[0] = *(const bf16x8*)&bs_[wc * 32 + al][kq * 8];
        bfr[1] = *(const bf16x8*)&bs_[wc * 32 + 16 + al][kq * 8];

        for (int mi = 0; mi < 2; ++mi)
            for (int ni = 0; ni < 2; ++ni)
                acc[mi][ni] = __builtin_amdgcn_mfma_f32_16x16x32_bf16(
                    af[mi], bfr[ni], acc[mi][ni], 0, 0, 0);
    }

    // epilogue: C/D layout col=lane&15, row=(lane>>4)*4+i  [m89/m91 verified]
    for (int mi = 0; mi < 2; ++mi) {
        for (int ni = 0; ni < 2; ++ni) {
            const int gcol = bn * 64 + wc * 32 + ni * 16 + al;
            const float bv = bias ? bias[gcol] : 0.f;
            for (int i = 0; i < 4; ++i) {
                const int grow = bm * 64 + wr * 32 + mi * 16 + kq * 4 + i;
                float v = acc[mi][ni][i] + bv;
                if (ACT == ACT_RELU)  v = fmaxf(v, 0.f);
                if (ACT == ACT_RELU2) { v = fmaxf(v, 0.f); v = v * v; }
                if (TRANSOUT) {
                    const int b = grow >> 10, s = grow & 1023;
                    C[((size_t)b * N + gcol) * 1024 + s] = v;
                } else {
                    C[(size_t)grow * N + gcol] = v;
                }
            }
        }
    }
}

// ---------------- workspace init ----------------
__global__ void init_ws(float* hbuf, int* flags) {
    int t = blockIdx.x * 256 + threadIdx.x;
    if (t < 4096) hbuf[t] = 0.f;
    if (t < 128 * 32) flags[t] = 0;
}

// ---------------- GRU persistent kernel ----------------
// 128 WGs x 256 threads, co-resident. WG wg owns hidden units u0=wg*8 .. u0+7.
// LDS holds 24 rows (r,z,n for its 8 units) of w_hh as bf16 (48KB).
// Lock-step over 1024 steps via per-WG flag words + agent-scope fences.
__global__ __launch_bounds__(256, 1) void gru_kernel(
    const float* __restrict__ xp,     // [2048][3072], row = b*1024+t, with b_ih added
    const float* __restrict__ w_hh,   // [3072][1024]
    const float* __restrict__ b_hh,   // [3072]
    float* __restrict__ states,       // [2048][1024]
    float* __restrict__ hbuf,         // 2 x [2][1024]
    int* __restrict__ flags)          // 128 slots, stride 32 ints
{
    __shared__ unsigned short wlds[24 * 1024];  // bf16 weights
    __shared__ float ghs[24][2];
    __shared__ float bh[24];

    const int wg = blockIdx.x, tid = threadIdx.x;
    const int u0 = wg * 8;

    for (int idx = tid; idx < 24 * 1024; idx += 256) {
        const int rr = idx >> 10, kk = idx & 1023;
        const int grow = (rr < 8) ? (u0 + rr) : (rr < 16) ? (1024 + u0 + rr - 8) : (2048 + u0 + rr - 16);
        wlds[idx] = f2bf(w_hh[((size_t)grow << 10) | kk]);
    }
    if (tid < 24) {
        const int rr = tid;
        const int grow = (rr < 8) ? (u0 + rr) : (rr < 16) ? (1024 + u0 + rr - 8) : (2048 + u0 + rr - 16);
        bh[rr] = b_hh[grow];
    }
    __syncthreads();

    const int w = tid >> 6, lane = tid & 63;
    float* h0 = hbuf;
    float* h1 = hbuf + 2048;

    for (int t = 0; t < 1024; ++t) {
        const float* hp = (t & 1) ? h1 : h0;
        float* hn = (t & 1) ? h0 : h1;

        // load h_prev chunks this lane needs: elements (c*64+lane)*8 .. +7, c=0,1, per batch
        float4 hr_[2][2][2];
        for (int b = 0; b < 2; ++b) {
            const float4* hp4 = (const float4*)(hp + (b << 10));
            for (int c = 0; c < 2; ++c) {
                hr_[b][c][0] = hp4[c * 128 + (lane << 1)];
                hr_[b][c][1] = hp4[c * 128 + (lane << 1) + 1];
            }
        }

        // 6 rows per wave; each row = dot(w_row, h[b]) for b=0,1
        for (int rr6 = 0; rr6 < 6; ++rr6) {
            const int rr = w * 6 + rr6;
            const uint4* wr4 = (const uint4*)&wlds[rr << 10];
            float p0 = 0.f, p1 = 0.f;
            for (int c = 0; c < 2; ++c) {
                const uint4 wv = wr4[c * 64 + lane];
                const float w0 = bf_lo(wv.x), w1 = bf_hi(wv.x);
                const float w2 = bf_lo(wv.y), w3 = bf_hi(wv.y);
                const float w4 = bf_lo(wv.z), w5 = bf_hi(wv.z);
                const float w6 = bf_lo(wv.w), w7 = bf_hi(wv.w);
                {
                    const float4 ha = hr_[0][c][0], hb = hr_[0][c][1];
                    p0 += w0 * ha.x + w1 * ha.y + w2 * ha.z + w3 * ha.w
                        + w4 * hb.x + w5 * hb.y + w6 * hb.z + w7 * hb.w;
                }
                {
                    const float4 ha = hr_[1][c][0], hb = hr_[1][c][1];
                    p1 += w0 * ha.x + w1 * ha.y + w2 * ha.z + w3 * ha.w
                        + w4 * hb.x + w5 * hb.y + w6 * hb.z + w7 * hb.w;
                }
            }
            for (int off = 32; off > 0; off >>= 1) {
                p0 += __shfl_xor(p0, off);
                p1 += __shfl_xor(p1, off);
            }
            if (lane == 0) { ghs[rr][0] = p0; ghs[rr][1] = p1; }
        }
        __syncthreads();

        if (tid < 16) {
            const int j = tid & 7, b = tid >> 3;
            const int row = (b << 10) | t;
            const float* xr = xp + (size_t)row * 3072;
            const float ir = xr[u0 + j], iz = xr[1024 + u0 + j], inn = xr[2048 + u0 + j];
            const float hr = ghs[j][b] + bh[j];
            const float hz = ghs[8 + j][b] + bh[8 + j];
            const float hnv = ghs[16 + j][b] + bh[16 + j];
            const float rg = 1.f / (1.f + __expf(-(ir + hr)));
            const float zg = 1.f / (1.f + __expf(-(iz + hz)));
            const float ng = tanhf(inn + rg * hnv);
            const float hprev = hp[(b << 10) + u0 + j];
            const float hnew = (1.f - zg) * ng + zg * hprev;
            hn[(b << 10) + u0 + j] = hnew;
            states[(size_t)row * 1024 + u0 + j] = hnew;
        }

        // device-wide lock-step barrier
        __syncthreads();
        if (tid == 0) {
            __threadfence();  // release: flush this XCD's L2 so h_next is agent-visible
            __hip_atomic_store(&flags[wg << 5], t + 1, __ATOMIC_RELEASE, __HIP_MEMORY_SCOPE_AGENT);
        }
        if (tid < 128) {
            while (__hip_atomic_load(&flags[tid << 5], __ATOMIC_RELAXED, __HIP_MEMORY_SCOPE_AGENT) <= t) { }
        }
        __syncthreads();
        __threadfence();      // acquire: invalidate caches before reading other WGs' h
    }
}

// ---------------- gate = sigmoid(states @ Wg^T + bg), one wave per row ----------------
__global__ __launch_bounds__(256) void gate_kernel(
    const float* __restrict__ states, const float* __restrict__ Wg,
    const float* __restrict__ bg, float* __restrict__ gate)
{
    const int w = threadIdx.x >> 6, lane = threadIdx.x & 63;
    const int row = blockIdx.x * 4 + w;
    const float4* sr = (const float4*)(states + (size_t)row * 1024);
    const float4* wr = (const float4*)Wg;
    float p = 0.f;
    for (int c = 0; c < 4; ++c) {
        const float4 sv = sr[c * 64 + lane];
        const float4 wv = wr[c * 64 + lane];
        p += sv.x * wv.x + sv.y * wv.y + sv.z * wv.z + sv.w * wv.w;
    }
    for (int off = 32; off > 0; off >>= 1) p += __shfl_xor(p, off);
    if (lane == 0) gate[row] = 1.f / (1.f + __expf(-(p + bg[0])));
}

// ---------------- combined = base + gate * residual ----------------
__global__ __launch_bounds__(256) void combined_kernel(
    const float* __restrict__ base, const float* __restrict__ resid,
    const float* __restrict__ gate, float* __restrict__ comb)
{
    const int idx = blockIdx.x * 256 + threadIdx.x;
    const int row = idx >> 9;
    comb[idx] = base[idx] + gate[row] * resid[idx];
}

// ---------------- attention + scatter into logits ----------------
// Block (i, b): softmax over j<i of q_i . k_j / 16, times gate*memory_scale,
// atomicAdd into out[b,i, ids[b,j]].
__global__ __launch_bounds__(256) void attn_scatter(
    const float* __restrict__ q,      // [2048][256]
    const float* __restrict__ kT,     // [2][256][1024]
    const float* __restrict__ gate,   // [2048]
    const float* __restrict__ mscale, // [1]
    const int* __restrict__ ids,      // [2][1024]
    float* __restrict__ out)          // [2][1024][32000]
{
    const int i = blockIdx.x, b = blockIdx.y, t = threadIdx.x;
    if (i == 0) return;
    __shared__ float qs[256];
    __shared__ float red[256];

    qs[t] = q[((size_t)((b << 10) | i)) * 256 + t];
    __syncthreads();

    const int j0 = t * 4;
    float s[4] = {0.f, 0.f, 0.f, 0.f};
    const float* kb = kT + (size_t)b * 256 * 1024;
    if (j0 < i) {
        for (int kk = 0; kk < 256; ++kk) {
            const float qv = qs[kk];
            const float4 kv = *(const float4*)(kb + (size_t)kk * 1024 + j0);
            s[0] += qv * kv.x; s[1] += qv * kv.y; s[2] += qv * kv.z; s[3] += qv * kv.w;
        }
    }
    const float scale = 0.0625f;  // 1/sqrt(256)
    float mx = -1e30f;
    for (int e = 0; e < 4; ++e)
        if (j0 + e < i) { s[e] *= scale; mx = fmaxf(mx, s[e]); }

    red[t] = mx; __syncthreads();
    for (int o = 128; o > 0; o >>= 1) {
        if (t < o) red[t] = fmaxf(red[t], red[t + o]);
        __syncthreads();
    }
    const float m = red[0];
    __syncthreads();

    float p[4]; float ssum = 0.f;
    for (int e = 0; e < 4; ++e) {
        if (j0 + e < i) { p[e] = __expf(s[e] - m); ssum += p[e]; }
        else p[e] = 0.f;
    }
    red[t] = ssum; __syncthreads();
    for (int o = 128; o > 0; o >>= 1) {
        if (t < o) red[t] += red[t + o];
        __syncthreads();
    }
    const float denom = fmaxf(red[0], 1e-6f);
    const float g6 = gate[(b << 10) | i] * mscale[0] / denom;

    float* orow = out + ((size_t)((b << 10) | i)) * 32000;
    const int* idr = ids + (b << 10);
    for (int e = 0; e < 4; ++e)
        if (j0 + e < i) atomicAdd(&orow[idr[j0 + e]], p[e] * g6);
}

// ---------------- launch ----------------
extern "C" void kernel_launch(void* const* d_in, const int* in_sizes, int n_in,
                              void* d_out, int out_size, void* d_ws, size_t ws_size,
                              hipStream_t stream)
{
    const int*   ids     = (const int*)  d_in[0];   // [2,1024]
    const float* emb_W   = (const float*)d_in[1];   // [32000,512]
    const float* w_ih    = (const float*)d_in[2];   // [3072,512]
    const float* w_hh    = (const float*)d_in[3];   // [3072,1024]
    const float* b_ih    = (const float*)d_in[4];
    const float* b_hh    = (const float*)d_in[5];
    const float* Wq      = (const float*)d_in[6];   // [256,1024]
    const float* bq      = (const float*)d_in[7];
    const float* Wk      = (const float*)d_in[8];
    const float* bk      = (const float*)d_in[9];
    const float* Wg      = (const float*)d_in[10];  // [1,1024]
    const float* bg      = (const float*)d_in[11];
    const float* W1      = (const float*)d_in[12];  // [2048,1024]
    const float* b1      = (const float*)d_in[13];
    const float* W2      = (const float*)d_in[14];  // [512,2048]
    const float* b2      = (const float*)d_in[15];
    const float* Wr      = (const float*)d_in[16];  // [512,512]
    const float* br      = (const float*)d_in[17];
    const float* mscale  = (const float*)d_in[18];
    const float* out_b   = (const float*)d_in[19];  // [32000]
    float* out = (float*)d_out;

    float* ws = (float*)d_ws;
    float* xp     = ws;                         // 2048*3072
    float* states = xp     + (size_t)2048 * 3072;
    float* hf     = states + (size_t)2048 * 1024;
    float* base   = hf     + (size_t)2048 * 2048;
    float* resid  = base   + (size_t)2048 * 512;
    float* qv     = resid  + (size_t)2048 * 512;
    float* kT     = qv     + (size_t)2048 * 256;
    float* comb   = kT     + (size_t)2 * 256 * 1024;
    float* gate   = comb   + (size_t)2048 * 512;
    float* hbuf   = gate   + 2048;              // 4096 floats
    int*   flags  = (int*)(hbuf + 4096);        // 128*32 ints

    dim3 blk(256);

    // 1) xp = emb_W[ids] @ w_ih^T + b_ih
    gemm_bt<ACT_NONE, true, false><<<dim3(32, 48), blk, 0, stream>>>(
        emb_W, w_ih, b_ih, xp, ids, 2048, 3072, 512);

    // 2) GRU
    init_ws<<<16, blk, 0, stream>>>(hbuf, flags);
    gru_kernel<<<128, blk, 0, stream>>>(xp, w_hh, b_hh, states, hbuf, flags);

    // 3) hf = relu(states @ W1^T + b1)^2
    gemm_bt<ACT_RELU2, false, false><<<dim3(32, 32), blk, 0, stream>>>(
        states, W1, b1, hf, nullptr, 2048, 2048, 1024);

    // 4) base = hf @ W2^T + b2
    gemm_bt<ACT_NONE, false, false><<<dim3(32, 8), blk, 0, stream>>>(
        hf, W2, b2, base, nullptr, 2048, 512, 2048);

    // 5) residual = relu(base @ Wr^T + br)
    gemm_bt<ACT_RELU, false, false><<<dim3(32, 8), blk, 0, stream>>>(
        base, Wr, br, resid, nullptr, 2048, 512, 512);

    // 6) gate
    gate_kernel<<<512, blk, 0, stream>>>(states, Wg, bg, gate);

    // 7) q, kT
    gemm_bt<ACT_NONE, false, false><<<dim3(32, 4), blk, 0, stream>>>(
        states, Wq, bq, qv, nullptr, 2048, 256, 1024);
    gemm_bt<ACT_NONE, false, true><<<dim3(32, 4), blk, 0, stream>>>(
        states, Wk, bk, kT, nullptr, 2048, 256, 1024);

    // 8) combined = base + gate*residual
    combined_kernel<<<4096, blk, 0, stream>>>(base, resid, gate, comb);

    // 9) logits = combined @ emb_W^T + output_bias   (fused base+residual head)
    gemm_bt<ACT_NONE, false, false><<<dim3(32, 500), blk, 0, stream>>>(
        comb, emb_W, out_b, out, nullptr, 2048, 32000, 512);

    // 10) attention softmax + scatter-add into logits
    attn_scatter<<<dim3(1024, 2), blk, 0, stream>>>(qv, kT, gate, mscale, ids, out);
}

// Round 2
// 6446.407 us; speedup vs baseline: 2.4066x; 2.4066x over previous
//
#include <hip/hip_runtime.h>
#include <math.h>

// ---------------- common types ----------------
typedef __attribute__((ext_vector_type(8))) short bf16x8;
typedef __attribute__((ext_vector_type(4))) float f32x4;

__device__ __forceinline__ unsigned short f2bf(float x) {
    unsigned u = __float_as_uint(x);
    unsigned r = (u + 0x7FFF + ((u >> 16) & 1)) >> 16;
    return (unsigned short)r;
}
__device__ __forceinline__ float bf_lo(unsigned u) { return __uint_as_float(u << 16); }
__device__ __forceinline__ float bf_hi(unsigned u) { return __uint_as_float(u & 0xffff0000u); }

#define ACT_NONE  0
#define ACT_RELU  1
#define ACT_RELU2 2

// ---------------- MFMA GEMM: C[M,N] = act(A[M,K] @ B[N,K]^T + bias[N]) ----------------
// 64x64 tile, BK=32, 256 threads (4 waves, each 32x32 via 2x2 of 16x16x32 mfma).
template <int ACT, bool GATHER, bool TRANSOUT>
__global__ __launch_bounds__(256) void gemm_bt(
    const float* __restrict__ A, const float* __restrict__ Bm,
    const float* __restrict__ bias, float* __restrict__ C,
    const int* __restrict__ ids, int M, int N, int K)
{
    __shared__ unsigned short as_[64][40];
    __shared__ unsigned short bs_[64][40];

    const int tid = threadIdx.x;
    const int bm = blockIdx.x, bn = blockIdx.y;
    const int r = tid >> 2, seg = tid & 3;

    const int arow = bm * 64 + r;
    const float* aptr = GATHER ? (A + (size_t)ids[arow] * K) : (A + (size_t)arow * K);
    const float* bptr = Bm + (size_t)(bn * 64 + r) * K;

    const int w = tid >> 6, lane = tid & 63;
    const int wr = w >> 1, wc = w & 1;
    const int al = lane & 15, kq = lane >> 4;

    f32x4 acc[2][2];
    for (int mi = 0; mi < 2; ++mi)
        for (int ni = 0; ni < 2; ++ni)
            acc[mi][ni] = (f32x4){0.f, 0.f, 0.f, 0.f};

    for (int k0 = 0; k0 < K; k0 += 32) {
        __syncthreads();
        {
            const float4* ap4 = (const float4*)(aptr + k0 + seg * 8);
            float4 a0 = ap4[0], a1 = ap4[1];
            uint4 pk;
            pk.x = (unsigned)f2bf(a0.x) | ((unsigned)f2bf(a0.y) << 16);
            pk.y = (unsigned)f2bf(a0.z) | ((unsigned)f2bf(a0.w) << 16);
            pk.z = (unsigned)f2bf(a1.x) | ((unsigned)f2bf(a1.y) << 16);
            pk.w = (unsigned)f2bf(a1.z) | ((unsigned)f2bf(a1.w) << 16);
            *(uint4*)&as_[r][seg * 8] = pk;

            const float4* bp4 = (const float4*)(bptr + k0 + seg * 8);
            float4 b0 = bp4[0], b1 = bp4[1];
            pk.x = (unsigned)f2bf(b0.x) | ((unsigned)f2bf(b0.y) << 16);
            pk.y = (unsigned)f2bf(b0.z) | ((unsigned)f2bf(b0.w) << 16);
            pk.z = (unsigned)f2bf(b1.x) | ((unsigned)f2bf(b1.y) << 16);
            pk.w = (unsigned)f2bf(b1.z) | ((unsigned)f2bf(b1.w) << 16);
            *(uint4*)&bs_[r][seg * 8] = pk;
        }
        __syncthreads();

        bf16x8 af[2], bfr[2];
        af[0]  = *(const bf16x8*)&as_[wr * 32 + al][kq * 8];
        af[1]  = *(const bf16x8*)&as_[wr * 32 + 16 + al][kq * 8];
        bfr[0] = *(const bf16x8*)&bs_[wc * 32 + al][kq * 8];
        bfr[1] = *(const bf16x8*)&bs_[wc * 32 + 16 + al][kq * 8];

        for (int mi = 0; mi < 2; ++mi)
            for (int ni = 0; ni < 2; ++ni)
                acc[mi][ni] = __builtin_amdgcn_mfma_f32_16x16x32_bf16(
                    af[mi], bfr[ni], acc[mi][ni], 0, 0, 0);
    }

    for (int mi = 0; mi < 2; ++mi) {
        for (int ni = 0; ni < 2; ++ni) {
            const int gcol = bn * 64 + wc * 32 + ni * 16 + al;
            const float bv = bias ? bias[gcol] : 0.f;
            for (int i = 0; i < 4; ++i) {
                const int grow = bm * 64 + wr * 32 + mi * 16 + kq * 4 + i;
                float v = acc[mi][ni][i] + bv;
                if (ACT == ACT_RELU)  v = fmaxf(v, 0.f);
                if (ACT == ACT_RELU2) { v = fmaxf(v, 0.f); v = v * v; }
                if (TRANSOUT) {
                    const int b = grow >> 10, s = grow & 1023;
                    C[((size_t)b * N + gcol) * 1024 + s] = v;
                } else {
                    C[(size_t)grow * N + gcol] = v;
                }
            }
        }
    }
}

// ---------------- workspace init ----------------
__global__ void init_ws(float* hbuf, int* flags) {
    int t = blockIdx.x * 256 + threadIdx.x;
    if (t < 4096) hbuf[t] = 0.f;
    if (t < 128 * 32) flags[t] = 0;
}

// ---------------- GRU persistent kernel ----------------
// 128 WGs x 256 threads, co-resident. WG wg owns hidden units u0=wg*8 .. u0+7.
// LDS: 24 rows of w_hh (bf16, 48KB) + h mirror (8KB).
// Cross-WG exchange rides the MALL explicitly (sc0 sc1); no __threadfence.
__global__ __launch_bounds__(256, 1) void gru_kernel(
    const float* __restrict__ xp,     // [2048][3072], row = b*1024+t (b_ih added)
    const float* __restrict__ w_hh,   // [3072][1024]
    const float* __restrict__ b_hh,   // [3072]
    float* __restrict__ states,       // [2048][1024]
    float* __restrict__ hbuf,         // 2 x [2][1024] (buf0 zero-initialized)
    int* __restrict__ cnt)            // single MALL barrier counter (init 0)
{
    __shared__ unsigned short wlds[24 * 1024];  // bf16 weights
    __shared__ float hs_[2048];                 // h mirror [2][1024]
    __shared__ float ghs[24][2];
    __shared__ float bh[24];

    const int wg = blockIdx.x, tid = threadIdx.x;
    const int u0 = wg * 8;

    for (int idx = tid; idx < 24 * 1024; idx += 256) {
        const int rr = idx >> 10, kk = idx & 1023;
        const int grow = (rr < 8) ? (u0 + rr) : (rr < 16) ? (1024 + u0 + rr - 8) : (2048 + u0 + rr - 16);
        wlds[idx] = f2bf(w_hh[((size_t)grow << 10) | kk]);
    }
    if (tid < 24) {
        const int rr = tid;
        const int grow = (rr < 8) ? (u0 + rr) : (rr < 16) ? (1024 + u0 + rr - 8) : (2048 + u0 + rr - 16);
        bh[rr] = b_hh[grow];
    }
    __syncthreads();

    const int w = tid >> 6, lane = tid & 63;

    for (int t = 0; t < 1024; ++t) {
        const int p = t & 1;
        const float* src = hbuf + p * 2048;
        float* dst = hbuf + (1 - p) * 2048;

        // ---- stage h from MALL into LDS: 512 float4, 2 per thread, sc0 sc1 ----
        {
            const f32x4* hp4 = (const f32x4*)src;
            f32x4 ha, hb;
            asm volatile(
                "global_load_dwordx4 %0, %2, off sc0 sc1\n\t"
                "global_load_dwordx4 %1, %3, off sc0 sc1\n\t"
                "s_waitcnt vmcnt(0)"
                : "=&v"(ha), "=&v"(hb)
                : "v"(hp4 + tid), "v"(hp4 + 256 + tid)
                : "memory");
            ((f32x4*)hs_)[tid] = ha;
            ((f32x4*)hs_)[256 + tid] = hb;
        }
        __syncthreads();

        // ---- registers: this lane's 16 h elements per batch ----
        f32x4 hr_[2][2][2];
        for (int b = 0; b < 2; ++b) {
            const f32x4* hp4 = (const f32x4*)(hs_ + (b << 10));
            for (int c = 0; c < 2; ++c) {
                hr_[b][c][0] = hp4[c * 128 + (lane << 1)];
                hr_[b][c][1] = hp4[c * 128 + (lane << 1) + 1];
            }
        }

        // ---- 6 rows per wave: gh[rr][b] = dot(w_row, h[b]) ----
        for (int rr6 = 0; rr6 < 6; ++rr6) {
            const int rr = w * 6 + rr6;
            const uint4* wr4 = (const uint4*)&wlds[rr << 10];
            float p0 = 0.f, p1 = 0.f;
            for (int c = 0; c < 2; ++c) {
                const uint4 wv = wr4[c * 64 + lane];
                const float w0 = bf_lo(wv.x), w1 = bf_hi(wv.x);
                const float w2 = bf_lo(wv.y), w3 = bf_hi(wv.y);
                const float w4 = bf_lo(wv.z), w5 = bf_hi(wv.z);
                const float w6 = bf_lo(wv.w), w7 = bf_hi(wv.w);
                {
                    const f32x4 ha = hr_[0][c][0], hb2 = hr_[0][c][1];
                    p0 += w0 * ha.x + w1 * ha.y + w2 * ha.z + w3 * ha.w
                        + w4 * hb2.x + w5 * hb2.y + w6 * hb2.z + w7 * hb2.w;
                }
                {
                    const f32x4 ha = hr_[1][c][0], hb2 = hr_[1][c][1];
                    p1 += w0 * ha.x + w1 * ha.y + w2 * ha.z + w3 * ha.w
                        + w4 * hb2.x + w5 * hb2.y + w6 * hb2.z + w7 * hb2.w;
                }
            }
            for (int off = 32; off > 0; off >>= 1) {
                p0 += __shfl_xor(p0, off);
                p1 += __shfl_xor(p1, off);
            }
            if (lane == 0) { ghs[rr][0] = p0; ghs[rr][1] = p1; }
        }
        __syncthreads();

        // ---- pointwise update for our 8 units x 2 batches; publish to MALL ----
        if (tid < 16) {
            const int j = tid & 7, b = tid >> 3;
            const int row = (b << 10) | t;
            const float* xr = xp + (size_t)row * 3072;
            const float ir = xr[u0 + j], iz = xr[1024 + u0 + j], inn = xr[2048 + u0 + j];
            const float hr = ghs[j][b] + bh[j];
            const float hz = ghs[8 + j][b] + bh[8 + j];
            const float hnv = ghs[16 + j][b] + bh[16 + j];
            const float rg = 1.f / (1.f + __expf(-(ir + hr)));
            const float zg = 1.f / (1.f + __expf(-(iz + hz)));
            const float ng = tanhf(inn + rg * hnv);
            const float hprev = hs_[(b << 10) + u0 + j];
            const float hnew = (1.f - zg) * ng + zg * hprev;
            states[(size_t)row * 1024 + u0 + j] = hnew;
            __hip_atomic_store(&dst[(b << 10) + u0 + j], hnew,
                               __ATOMIC_RELAXED, __HIP_MEMORY_SCOPE_AGENT);
            asm volatile("s_waitcnt vmcnt(0)" ::: "memory");
        }
        __syncthreads();

        // ---- device barrier: one MALL counter, one arrival + one poller per WG ----
        if (tid == 0) {
            __hip_atomic_fetch_add(cnt, 1, __ATOMIC_RELAXED, __HIP_MEMORY_SCOPE_AGENT);
            while (__hip_atomic_load(cnt, __ATOMIC_RELAXED, __HIP_MEMORY_SCOPE_AGENT)
                   < 128 * (t + 1)) {
                __builtin_amdgcn_s_sleep(1);
            }
        }
        __syncthreads();
    }
}

// ---------------- gate = sigmoid(states @ Wg^T + bg), one wave per row ----------------
__global__ __launch_bounds__(256) void gate_kernel(
    const float* __restrict__ states, const float* __restrict__ Wg,
    const float* __restrict__ bg, float* __restrict__ gate)
{
    const int w = threadIdx.x >> 6, lane = threadIdx.x & 63;
    const int row = blockIdx.x * 4 + w;
    const float4* sr = (const float4*)(states + (size_t)row * 1024);
    const float4* wr = (const float4*)Wg;
    float p = 0.f;
    for (int c = 0; c < 4; ++c) {
        const float4 sv = sr[c * 64 + lane];
        const float4 wv = wr[c * 64 + lane];
        p += sv.x * wv.x + sv.y * wv.y + sv.z * wv.z + sv.w * wv.w;
    }
    for (int off = 32; off > 0; off >>= 1) p += __shfl_xor(p, off);
    if (lane == 0) gate[row] = 1.f / (1.f + __expf(-(p + bg[0])));
}

// ---------------- combined = base + gate * residual ----------------
__global__ __launch_bounds__(256) void combined_kernel(
    const float* __restrict__ base, const float* __restrict__ resid,
    const float* __restrict__ gate, float* __restrict__ comb)
{
    const int idx = blockIdx.x * 256 + threadIdx.x;
    const int row = idx >> 9;
    comb[idx] = base[idx] + gate[row] * resid[idx];
}

// ---------------- attention + scatter into logits ----------------
__global__ __launch_bounds__(256) void attn_scatter(
    const float* __restrict__ q,      // [2048][256]
    const float* __restrict__ kT,     // [2][256][1024]
    const float* __restrict__ gate,   // [2048]
    const float* __restrict__ mscale, // [1]
    const int* __restrict__ ids,      // [2][1024]
    float* __restrict__ out)          // [2][1024][32000]
{
    const int i = blockIdx.x, b = blockIdx.y, t = threadIdx.x;
    if (i == 0) return;
    __shared__ float qs[256];
    __shared__ float red[256];

    qs[t] = q[((size_t)((b << 10) | i)) * 256 + t];
    __syncthreads();

    const int j0 = t * 4;
    float s[4] = {0.f, 0.f, 0.f, 0.f};
    const float* kb = kT + (size_t)b * 256 * 1024;
    if (j0 < i) {
        for (int kk = 0; kk < 256; ++kk) {
            const float qv = qs[kk];
            const float4 kv = *(const float4*)(kb + (size_t)kk * 1024 + j0);
            s[0] += qv * kv.x; s[1] += qv * kv.y; s[2] += qv * kv.z; s[3] += qv * kv.w;
        }
    }
    const float scale = 0.0625f;  // 1/sqrt(256)
    float mx = -1e30f;
    for (int e = 0; e < 4; ++e)
        if (j0 + e < i) { s[e] *= scale; mx = fmaxf(mx, s[e]); }

    red[t] = mx; __syncthreads();
    for (int o = 128; o > 0; o >>= 1) {
        if (t < o) red[t] = fmaxf(red[t], red[t + o]);
        __syncthreads();
    }
    const float m = red[0];
    __syncthreads();

    float p[4]; float ssum = 0.f;
    for (int e = 0; e < 4; ++e) {
        if (j0 + e < i) { p[e] = __expf(s[e] - m); ssum += p[e]; }
        else p[e] = 0.f;
    }
    red[t] = ssum; __syncthreads();
    for (int o = 128; o > 0; o >>= 1) {
        if (t < o) red[t] += red[t + o];
        __syncthreads();
    }
    const float denom = fmaxf(red[0], 1e-6f);
    const float g6 = gate[(b << 10) | i] * mscale[0] / denom;

    float* orow = out + ((size_t)((b << 10) | i)) * 32000;
    const int* idr = ids + (b << 10);
    for (int e = 0; e < 4; ++e)
        if (j0 + e < i) atomicAdd(&orow[idr[j0 + e]], p[e] * g6);
}

// ---------------- launch ----------------
extern "C" void kernel_launch(void* const* d_in, const int* in_sizes, int n_in,
                              void* d_out, int out_size, void* d_ws, size_t ws_size,
                              hipStream_t stream)
{
    const int*   ids     = (const int*)  d_in[0];
    const float* emb_W   = (const float*)d_in[1];
    const float* w_ih    = (const float*)d_in[2];
    const float* w_hh    = (const float*)d_in[3];
    const float* b_ih    = (const float*)d_in[4];
    const float* b_hh    = (const float*)d_in[5];
    const float* Wq      = (const float*)d_in[6];
    const float* bq      = (const float*)d_in[7];
    const float* Wk      = (const float*)d_in[8];
    const float* bk      = (const float*)d_in[9];
    const float* Wg      = (const float*)d_in[10];
    const float* bg      = (const float*)d_in[11];
    const float* W1      = (const float*)d_in[12];
    const float* b1      = (const float*)d_in[13];
    const float* W2      = (const float*)d_in[14];
    const float* b2      = (const float*)d_in[15];
    const float* Wr      = (const float*)d_in[16];
    const float* br      = (const float*)d_in[17];
    const float* mscale  = (const float*)d_in[18];
    const float* out_b   = (const float*)d_in[19];
    float* out = (float*)d_out;

    float* ws = (float*)d_ws;
    float* xp     = ws;                         // 2048*3072
    float* states = xp     + (size_t)2048 * 3072;
    float* hf     = states + (size_t)2048 * 1024;
    float* base   = hf     + (size_t)2048 * 2048;
    float* resid  = base   + (size_t)2048 * 512;
    float* qv     = resid  + (size_t)2048 * 512;
    float* kT     = qv     + (size_t)2048 * 256;
    float* comb   = kT     + (size_t)2 * 256 * 1024;
    float* gate   = comb   + (size_t)2048 * 512;
    float* hbuf   = gate   + 2048;              // 4096 floats
    int*   flags  = (int*)(hbuf + 4096);        // cnt at flags[0]

    dim3 blk(256);

    gemm_bt<ACT_NONE, true, false><<<dim3(32, 48), blk, 0, stream>>>(
        emb_W, w_ih, b_ih, xp, ids, 2048, 3072, 512);

    init_ws<<<16, blk, 0, stream>>>(hbuf, flags);
    gru_kernel<<<128, blk, 0, stream>>>(xp, w_hh, b_hh, states, hbuf, flags);

    gemm_bt<ACT_RELU2, false, false><<<dim3(32, 32), blk, 0, stream>>>(
        states, W1, b1, hf, nullptr, 2048, 2048, 1024);

    gemm_bt<ACT_NONE, false, false><<<dim3(32, 8), blk, 0, stream>>>(
        hf, W2, b2, base, nullptr, 2048, 512, 2048);

    gemm_bt<ACT_RELU, false, false><<<dim3(32, 8), blk, 0, stream>>>(
        base, Wr, br, resid, nullptr, 2048, 512, 512);

    gate_kernel<<<512, blk, 0, stream>>>(states, Wg, bg, gate);

    gemm_bt<ACT_NONE, false, false><<<dim3(32, 4), blk, 0, stream>>>(
        states, Wq, bq, qv, nullptr, 2048, 256, 1024);
    gemm_bt<ACT_NONE, false, true><<<dim3(32, 4), blk, 0, stream>>>(
        states, Wk, bk, kT, nullptr, 2048, 256, 1024);

    combined_kernel<<<4096, blk, 0, stream>>>(base, resid, gate, comb);

    gemm_bt<ACT_NONE, false, false><<<dim3(32, 500), blk, 0, stream>>>(
        comb, emb_W, out_b, out, nullptr, 2048, 32000, 512);

    attn_scatter<<<dim3(1024, 2), blk, 0, stream>>>(qv, kT, gate, mscale, ids, out);
}